// Round 10
// baseline (100.857 us; speedup 1.0000x reference)
//
#include <hip/hip_runtime.h>
#include <math.h>

#define NG 9
#define NBLK 1024          // pair blocks: 4/CU
#define JT 32              // j-tile width
#define ITILE 512          // i-fragment: 2 slots x 256 threads (packed f32x2)
#define LOG2E 1.4426950408889634f
#define LN2   0.6931471805599453f

typedef float f32x2 __attribute__((ext_vector_type(2)));

// ---------------------------------------------------------------------------
// Dispatch 1: ONE 1024-thread block classifies ALL rows and writes globally
// dense iLM/jLM + a 20-int header. In-block 16-wave ballot compaction with a
// running base in LDS: no memset, no atomics, and k_pairs needs no prefix
// table or binary search (dense lists, R7's proven cheapest form).
// hdr: [0]=nI, [1]=nJ, [2..10]=cT[g], [11..19]=cN[g]
// ---------------------------------------------------------------------------
__global__ __launch_bounds__(1024) void k_classify(
    const float* __restrict__ logits, const float* __restrict__ ytox,
    const float* __restrict__ yid, int B, int* __restrict__ hdr,
    float2* __restrict__ iLM, float2* __restrict__ jLM) {

    __shared__ int wT[16], wN[16], oT[16], oN[16];
    __shared__ int gTs[16][NG], gNs[16][NG];
    __shared__ int baseT, baseN;

    const int tid = threadIdx.x, lane = tid & 63, wave = tid >> 6;
    const unsigned long long lt = (1ull << lane) - 1ull;

    if (tid < 16 * NG) { gTs[tid / NG][tid % NG] = 0; gNs[tid / NG][tid % NG] = 0; }
    if (tid == 0) { baseT = 0; baseN = 0; }
    __syncthreads();

    const int nSl = (B + 1023) >> 10;
    for (int u = 0; u < nSl; ++u) {
        const int row = (u << 10) + tid;        // coalesced across the block
        const bool v = row < B;
        float l = 0.f; bool tox = false, non = false; int m = 0;
        if (v) {
            l = logits[row] * LOG2E;            // pre-scale: log2-domain softplus
            tox = ytox[row] >= 0.5f;
            non = !tox;
#pragma unroll
            for (int g = 0; g < NG; ++g)
                if (yid[row * NG + g] >= 0.5f) m |= 1 << g;
        }
        const unsigned long long bT = __ballot(tox), bN = __ballot(non);
        const int pT = __popcll(bT & lt), pN = __popcll(bN & lt);
        if (lane == 0) { wT[wave] = __popcll(bT); wN[wave] = __popcll(bN); }
#pragma unroll
        for (int g = 0; g < NG; ++g) {
            const unsigned long long bt = __ballot(tox && ((m >> g) & 1));
            const unsigned long long bn = __ballot(non && ((m >> g) & 1));
            if (lane == 0) { gTs[wave][g] += __popcll(bt); gNs[wave][g] += __popcll(bn); }
        }
        __syncthreads();                        // wT/wN ready for tid0
        if (tid == 0) {
            int a = baseT, b = baseN;
#pragma unroll
            for (int w = 0; w < 16; ++w) { oT[w] = a; a += wT[w]; oN[w] = b; b += wN[w]; }
            baseT = a; baseN = b;
        }
        __syncthreads();                        // oT/oN ready for all
        if (tox) iLM[oT[wave] + pT] = make_float2(l, __int_as_float(m));
        if (non) jLM[oN[wave] + pN] = make_float2(l, __int_as_float(m));
    }
    __syncthreads();
    if (tid == 0) { hdr[0] = baseT; hdr[1] = baseN; }
    if (tid < NG) {
        int s = 0;
#pragma unroll
        for (int w = 0; w < 16; ++w) s += gTs[w][tid];
        hdr[2 + tid] = s;
    } else if (tid >= 64 && tid < 64 + NG) {
        const int g = tid - 64;
        int s = 0;
#pragma unroll
        for (int w = 0; w < 16; ++w) s += gNs[w][g];
        hdr[11 + g] = s;
    }
}

// ---------------------------------------------------------------------------
// Dispatch 2: pair kernel over globally-dense lists (R7 verbatim) — no
// prefix, no search, packed-FP32 inner loop, plain partial stores.
// ---------------------------------------------------------------------------
__global__ __launch_bounds__(256, 4) void k_pairs(
    const int* __restrict__ hdr, const float2* __restrict__ iLM,
    const float2* __restrict__ jLM, float* __restrict__ part) {

    __shared__ float2 jS[JT];
    __shared__ float red[4][27];
    __shared__ float acc[27];

    const int tid = threadIdx.x, lane = tid & 63, wave = tid >> 6;
    const int blk = blockIdx.x;
    const int nI = hdr[0], nJ = hdr[1];
    const int nbI = (nI + ITILE - 1) / ITILE;
    const int nbJ = (nJ + JT - 1) / JT;
    const int nT = nbI * nbJ;

    if (tid < 27) acc[tid] = 0.f;

    f32x2 li = {1e30f, 1e30f};        // sentinel: exp2(-inf)=0 -> contributes 0
    int mi0 = 0, mi1 = 0;
    f32x2 Ra = {0.f, 0.f};
    f32x2 Rg[NG];
#pragma unroll
    for (int g = 0; g < NG; ++g) Rg[g] = (f32x2){0.f, 0.f};

    auto flush = [&]() {   // fold 2 packed slots x 9 groups into 27 block sums
#pragma unroll
        for (int g = 0; g < NG; ++g) {
            const bool i0 = (mi0 >> g) & 1, i1 = (mi1 >> g) & 1;
            const float r0 = Rg[g].x, r1 = Rg[g].y;
            float x0 = (i0 ? r0 : 0.f) + (i1 ? r1 : 0.f);
            float x1 = (i0 ? 0.f : r0) + (i1 ? 0.f : r1);
            float x2 = (i0 ? (Ra.x - r0) : 0.f) + (i1 ? (Ra.y - r1) : 0.f);
#pragma unroll
            for (int off = 32; off > 0; off >>= 1) {
                x0 += __shfl_xor(x0, off, 64);
                x1 += __shfl_xor(x1, off, 64);
                x2 += __shfl_xor(x2, off, 64);
            }
            if (lane == 0) {
                red[wave][g] = x0; red[wave][NG + g] = x1; red[wave][2 * NG + g] = x2;
            }
        }
        __syncthreads();
        if (tid < 27)
            acc[tid] += red[0][tid] + red[1][tid] + red[2][tid] + red[3][tid];
    };

    int prev_bi = -1;
    for (int t = blk; t < nT; t += NBLK) {
        const int bi = t % nbI, bj = t / nbI;   // j-major: bi stable per block
        if (bi != prev_bi) {
            if (prev_bi >= 0) flush();
            const int k0 = bi * ITILE + tid, k1 = k0 + 256;
            const float2 a0 = (k0 < nI) ? iLM[k0] : make_float2(1e30f, 0.f);
            const float2 a1 = (k1 < nI) ? iLM[k1] : make_float2(1e30f, 0.f);
            li.x = a0.x; mi0 = __float_as_int(a0.y);
            li.y = a1.x; mi1 = __float_as_int(a1.y);
            Ra = (f32x2){0.f, 0.f};
#pragma unroll
            for (int g = 0; g < NG; ++g) Rg[g] = (f32x2){0.f, 0.f};
            prev_bi = bi;
        }
        const int jbeg = bj * JT;
        const int jcnt = min(JT, nJ - jbeg);
        __syncthreads();                         // jS reuse + red/acc ordering
        if (tid < jcnt) jS[tid] = jLM[jbeg + tid];
        __syncthreads();
#pragma unroll 2
        for (int k = 0; k < jcnt; ++k) {
            const float2 jv = jS[k];                                  // b64 broadcast
            const int mj = __builtin_amdgcn_readfirstlane(__float_as_int(jv.y));
            const f32x2 ljv = {jv.x, jv.x};
            const f32x2 d = ljv - li;
            f32x2 e;
            e.x = __builtin_amdgcn_exp2f(d.x);                        // trans x2
            e.y = __builtin_amdgcn_exp2f(d.y);
            const f32x2 one = {1.f, 1.f};
            const f32x2 tpe = e + one;                                // v_pk_add
            f32x2 s;
            s.x = __builtin_amdgcn_logf(tpe.x);                       // trans x2
            s.y = __builtin_amdgcn_logf(tpe.y);
            Ra = Ra + s;                                              // v_pk_add
#pragma unroll
            for (int g = 0; g < NG; ++g) {
                const float bg = ((mj >> g) & 1) ? 1.f : 0.f;          // SGPR select
                const f32x2 bgv = {bg, bg};
                Rg[g] = __builtin_elementwise_fma(bgv, s, Rg[g]);      // v_pk_fma
            }
        }
    }
    if (prev_bi >= 0) flush();
    if (tid < 27) part[tid * NBLK + blk] = acc[tid];   // zeros when no tiles
}

// ---------------------------------------------------------------------------
// Dispatch 3: reduce 27 x NBLK partials (x ln2) + header counts + fp64 tail.
// ---------------------------------------------------------------------------
__global__ __launch_bounds__(512) void k_final(
    const float* __restrict__ part, const int* __restrict__ hdr,
    float* __restrict__ out) {
    __shared__ float fin[27];
    const int tid = threadIdx.x, lane = tid & 63, wave = tid >> 6;
    for (int r = wave; r < 27; r += 8) {
        float s = 0.f;
#pragma unroll
        for (int q = 0; q < NBLK / 64; ++q) s += part[r * NBLK + (q << 6) + lane];
#pragma unroll
        for (int off = 32; off > 0; off >>= 1) s += __shfl_xor(s, off, 64);
        if (lane == 0) fin[r] = s * LN2;     // undo log2-domain accumulation
    }
    __syncthreads();
    if (tid == 0) {
        const long long nT64 = hdr[0], nN64 = hdr[1];
        double accd = 0.0; int ngv = 0;
        for (int g = 0; g < NG; ++g) {
            const long long cT = hdr[2 + g], cN = hdr[11 + g];
            const long long c0 = cT * cN;
            const long long c1 = (nT64 - cT) * cN;
            const long long c2 = cT * (nN64 - cN);
            const double t0 = (double)fin[g]          / (double)(c0 > 0 ? c0 : 1);
            const double t1 = (double)fin[NG + g]     / (double)(c1 > 0 ? c1 : 1);
            const double t2 = (double)fin[2 * NG + g] / (double)(c2 > 0 ? c2 : 1);
            const int nv = (c0 > 0) + (c1 > 0) + (c2 > 0);
            const double gl = ((c0 > 0 ? t0 : 0.0) + (c1 > 0 ? t1 : 0.0) +
                               (c2 > 0 ? t2 : 0.0)) / (double)(nv > 0 ? nv : 1);
            if (nv > 0) { const double g2 = gl * gl; accd += g2 * g2; ++ngv; }
        }
        const double mp = accd / (double)(ngv > 0 ? ngv : 1);
        const double loss = sqrt(sqrt(mp));  // ^(1/4)
        out[0] = (float)(ngv > 0 ? loss : 0.0);
    }
}

extern "C" void kernel_launch(void* const* d_in, const int* in_sizes, int n_in,
                              void* d_out, int out_size, void* d_ws, size_t ws_size,
                              hipStream_t stream) {
    const float* logits = (const float*)d_in[0];
    const float* ytox   = (const float*)d_in[1];
    const float* yid    = (const float*)d_in[2];
    const int B = in_sizes[0];

    char* ws = (char*)d_ws;
    int*    hdr  = (int*)ws;                      // 20 ints (pad to 128B)
    float2* iLM  = (float2*)(ws + 128);           // B float2
    float2* jLM  = iLM + B;                       // B float2
    float*  part = (float*)(jLM + B);             // 27*NBLK floats

    k_classify<<<dim3(1), dim3(1024), 0, stream>>>(logits, ytox, yid, B,
                                                   hdr, iLM, jLM);
    k_pairs<<<dim3(NBLK), dim3(256), 0, stream>>>(hdr, iLM, jLM, part);
    k_final<<<dim3(1), dim3(512), 0, stream>>>(part, hdr, (float*)d_out);
}

// Round 11
// 90.962 us; speedup vs baseline: 1.1088x; 1.1088x over previous
//
#include <hip/hip_runtime.h>
#include <math.h>

#define NG 9
#define NBLK 1024          // pair blocks: 4/CU
#define CHROWS 256         // classification chunk rows
#define NCHMAX 256         // supports B <= 65536
#define JT 32              // j-tile width
#define ITILE 512          // i-fragment: 2 slots x 256 threads (packed f32x2)
#define LOG2E 1.4426950408889634f
#define LN2   0.6931471805599453f

typedef float f32x2 __attribute__((ext_vector_type(2)));

// ---------------------------------------------------------------------------
// Dispatch 1: classify all rows once (32 blocks), globally DENSE compaction
// with NO atomics and NO memset: block c computes its dense base offset by
// redundantly counting toxic rows in [0, c*256) (coalesced, L2-hot, ~1 us
// worst block). The last block's running total IS nI/nJ -> plain-store hdr.
// Per-group counts are per-chunk plain stores (summed in k_final).
// hdr: [0]=nI, [1]=nJ
// ---------------------------------------------------------------------------
__global__ __launch_bounds__(256) void k_classify(
    const float* __restrict__ logits, const float* __restrict__ ytox,
    const float* __restrict__ yid, int B, int* __restrict__ hdr,
    int* __restrict__ gTc, int* __restrict__ gNc,
    float2* __restrict__ iLM, float2* __restrict__ jLM) {

    __shared__ int wT[4], wN[4], oT[4], oN[4];
    __shared__ int gT[4][NG], gN[4][NG];
    __shared__ int pre[4];

    const int tid = threadIdx.x, lane = tid & 63, wave = tid >> 6;
    const int c = blockIdx.x;
    const int nCh = gridDim.x;
    const unsigned long long lt = (1ull << lane) - 1ull;

    // ---- prefix: count toxic rows in preceding chunks (all of which are full) ----
    int myT = 0;
    for (int r = tid; r < c * CHROWS; r += 256) myT += (ytox[r] >= 0.5f) ? 1 : 0;
#pragma unroll
    for (int off = 32; off > 0; off >>= 1) myT += __shfl_xor(myT, off, 64);
    if (lane == 0) pre[wave] = myT;

    // ---- classify own chunk (R7 verbatim) ----
    const int row = c * CHROWS + tid;
    const bool v = row < B;
    float l = 0.f; bool tox = false, non = false; int m = 0;
    if (v) {
        l = logits[row] * LOG2E;          // pre-scale: softplus in log2 domain
        tox = ytox[row] >= 0.5f;
        non = !tox;
#pragma unroll
        for (int g = 0; g < NG; ++g)
            if (yid[row * NG + g] >= 0.5f) m |= 1 << g;
    }
    const unsigned long long bTox = __ballot(tox), bNon = __ballot(non);
    const int pT = __popcll(bTox & lt), pN = __popcll(bNon & lt);
    if (lane == 0) { wT[wave] = __popcll(bTox); wN[wave] = __popcll(bNon); }
#pragma unroll
    for (int g = 0; g < NG; ++g) {
        const unsigned long long bt = __ballot(tox && ((m >> g) & 1));
        const unsigned long long bn = __ballot(non && ((m >> g) & 1));
        if (lane == 0) { gT[wave][g] = __popcll(bt); gN[wave][g] = __popcll(bn); }
    }
    __syncthreads();
    if (tid == 0) {
        const int preT = pre[0] + pre[1] + pre[2] + pre[3];
        const int preN = c * CHROWS - preT;     // preceding chunks are all full
        int a = preT, b = preN;
#pragma unroll
        for (int w = 0; w < 4; ++w) { oT[w] = a; a += wT[w]; oN[w] = b; b += wN[w]; }
        if (c == nCh - 1) { hdr[0] = a; hdr[1] = b; }   // running total == global
    }
    __syncthreads();
    if (tox) iLM[oT[wave] + pT] = make_float2(l, __int_as_float(m));
    if (non) jLM[oN[wave] + pN] = make_float2(l, __int_as_float(m));
    if (tid < NG)
        gTc[c * NG + tid] = gT[0][tid] + gT[1][tid] + gT[2][tid] + gT[3][tid];
    else if (tid >= 64 && tid < 64 + NG) {
        const int g = tid - 64;
        gNc[c * NG + g] = gN[0][g] + gN[1][g] + gN[2][g] + gN[3][g];
    }
}

// ---------------------------------------------------------------------------
// Dispatch 2: pair kernel over globally-dense lists (R7 verbatim) — no
// prefix, no search, packed-FP32 inner loop, plain partial stores.
// ---------------------------------------------------------------------------
__global__ __launch_bounds__(256, 4) void k_pairs(
    const int* __restrict__ hdr, const float2* __restrict__ iLM,
    const float2* __restrict__ jLM, float* __restrict__ part) {

    __shared__ float2 jS[JT];
    __shared__ float red[4][27];
    __shared__ float acc[27];

    const int tid = threadIdx.x, lane = tid & 63, wave = tid >> 6;
    const int blk = blockIdx.x;
    const int nI = hdr[0], nJ = hdr[1];
    const int nbI = (nI + ITILE - 1) / ITILE;
    const int nbJ = (nJ + JT - 1) / JT;
    const int nT = nbI * nbJ;

    if (tid < 27) acc[tid] = 0.f;

    f32x2 li = {1e30f, 1e30f};        // sentinel: exp2(-inf)=0 -> contributes 0
    int mi0 = 0, mi1 = 0;
    f32x2 Ra = {0.f, 0.f};
    f32x2 Rg[NG];
#pragma unroll
    for (int g = 0; g < NG; ++g) Rg[g] = (f32x2){0.f, 0.f};

    auto flush = [&]() {   // fold 2 packed slots x 9 groups into 27 block sums
#pragma unroll
        for (int g = 0; g < NG; ++g) {
            const bool i0 = (mi0 >> g) & 1, i1 = (mi1 >> g) & 1;
            const float r0 = Rg[g].x, r1 = Rg[g].y;
            float x0 = (i0 ? r0 : 0.f) + (i1 ? r1 : 0.f);
            float x1 = (i0 ? 0.f : r0) + (i1 ? 0.f : r1);
            float x2 = (i0 ? (Ra.x - r0) : 0.f) + (i1 ? (Ra.y - r1) : 0.f);
#pragma unroll
            for (int off = 32; off > 0; off >>= 1) {
                x0 += __shfl_xor(x0, off, 64);
                x1 += __shfl_xor(x1, off, 64);
                x2 += __shfl_xor(x2, off, 64);
            }
            if (lane == 0) {
                red[wave][g] = x0; red[wave][NG + g] = x1; red[wave][2 * NG + g] = x2;
            }
        }
        __syncthreads();
        if (tid < 27)
            acc[tid] += red[0][tid] + red[1][tid] + red[2][tid] + red[3][tid];
    };

    int prev_bi = -1;
    for (int t = blk; t < nT; t += NBLK) {
        const int bi = t % nbI, bj = t / nbI;   // j-major: bi stable per block
        if (bi != prev_bi) {
            if (prev_bi >= 0) flush();
            const int k0 = bi * ITILE + tid, k1 = k0 + 256;
            const float2 a0 = (k0 < nI) ? iLM[k0] : make_float2(1e30f, 0.f);
            const float2 a1 = (k1 < nI) ? iLM[k1] : make_float2(1e30f, 0.f);
            li.x = a0.x; mi0 = __float_as_int(a0.y);
            li.y = a1.x; mi1 = __float_as_int(a1.y);
            Ra = (f32x2){0.f, 0.f};
#pragma unroll
            for (int g = 0; g < NG; ++g) Rg[g] = (f32x2){0.f, 0.f};
            prev_bi = bi;
        }
        const int jbeg = bj * JT;
        const int jcnt = min(JT, nJ - jbeg);
        __syncthreads();                         // jS reuse + red/acc ordering
        if (tid < jcnt) jS[tid] = jLM[jbeg + tid];
        __syncthreads();
#pragma unroll 2
        for (int k = 0; k < jcnt; ++k) {
            const float2 jv = jS[k];                                  // b64 broadcast
            const int mj = __builtin_amdgcn_readfirstlane(__float_as_int(jv.y));
            const f32x2 ljv = {jv.x, jv.x};
            const f32x2 d = ljv - li;
            f32x2 e;
            e.x = __builtin_amdgcn_exp2f(d.x);                        // trans x2
            e.y = __builtin_amdgcn_exp2f(d.y);
            const f32x2 one = {1.f, 1.f};
            const f32x2 tpe = e + one;                                // v_pk_add
            f32x2 s;
            s.x = __builtin_amdgcn_logf(tpe.x);                       // trans x2
            s.y = __builtin_amdgcn_logf(tpe.y);
            Ra = Ra + s;                                              // v_pk_add
#pragma unroll
            for (int g = 0; g < NG; ++g) {
                const float bg = ((mj >> g) & 1) ? 1.f : 0.f;          // SGPR select
                const f32x2 bgv = {bg, bg};
                Rg[g] = __builtin_elementwise_fma(bgv, s, Rg[g]);      // v_pk_fma
            }
        }
    }
    if (prev_bi >= 0) flush();
    if (tid < 27) part[tid * NBLK + blk] = acc[tid];   // zeros when no tiles
}

// ---------------------------------------------------------------------------
// Dispatch 3: reduce 27 x NBLK partials (x ln2) + per-chunk counts + fp64 tail.
// ---------------------------------------------------------------------------
__global__ __launch_bounds__(512) void k_final(
    const float* __restrict__ part, const int* __restrict__ hdr,
    const int* __restrict__ gTc, const int* __restrict__ gNc,
    int B, float* __restrict__ out) {

    __shared__ float fin[27];
    __shared__ int cTs[NG], cNs[NG];
    const int tid = threadIdx.x, lane = tid & 63, wave = tid >> 6;
    const int nCh = (B + CHROWS - 1) / CHROWS;

    for (int r = wave; r < 27; r += 8) {
        float s = 0.f;
#pragma unroll
        for (int q = 0; q < NBLK / 64; ++q) s += part[r * NBLK + (q << 6) + lane];
#pragma unroll
        for (int off = 32; off > 0; off >>= 1) s += __shfl_xor(s, off, 64);
        if (lane == 0) fin[r] = s * LN2;     // undo log2-domain accumulation
    }
    if (tid < NG) {
        int s = 0;
        for (int c = 0; c < nCh; ++c) s += gTc[c * NG + tid];
        cTs[tid] = s;
    } else if (tid >= 64 && tid < 64 + NG) {
        const int g = tid - 64;
        int s = 0;
        for (int c = 0; c < nCh; ++c) s += gNc[c * NG + g];
        cNs[g] = s;
    }
    __syncthreads();
    if (tid == 0) {
        const long long nT64 = hdr[0], nN64 = hdr[1];
        double accd = 0.0; int ngv = 0;
        for (int g = 0; g < NG; ++g) {
            const long long cT = cTs[g], cN = cNs[g];
            const long long c0 = cT * cN;
            const long long c1 = (nT64 - cT) * cN;
            const long long c2 = cT * (nN64 - cN);
            const double t0 = (double)fin[g]          / (double)(c0 > 0 ? c0 : 1);
            const double t1 = (double)fin[NG + g]     / (double)(c1 > 0 ? c1 : 1);
            const double t2 = (double)fin[2 * NG + g] / (double)(c2 > 0 ? c2 : 1);
            const int nv = (c0 > 0) + (c1 > 0) + (c2 > 0);
            const double gl = ((c0 > 0 ? t0 : 0.0) + (c1 > 0 ? t1 : 0.0) +
                               (c2 > 0 ? t2 : 0.0)) / (double)(nv > 0 ? nv : 1);
            if (nv > 0) { const double g2 = gl * gl; accd += g2 * g2; ++ngv; }
        }
        const double mp = accd / (double)(ngv > 0 ? ngv : 1);
        const double loss = sqrt(sqrt(mp));   // ^(1/4)
        out[0] = (float)(ngv > 0 ? loss : 0.0);
    }
}

extern "C" void kernel_launch(void* const* d_in, const int* in_sizes, int n_in,
                              void* d_out, int out_size, void* d_ws, size_t ws_size,
                              hipStream_t stream) {
    const float* logits = (const float*)d_in[0];
    const float* ytox   = (const float*)d_in[1];
    const float* yid    = (const float*)d_in[2];
    const int B = in_sizes[0];
    const int nCh = (B + CHROWS - 1) / CHROWS;

    char* ws = (char*)d_ws;
    int* hdr  = (int*)ws;                               // 2 ints (pad 128B)
    int* gTc  = hdr + 32;                               // NCHMAX*NG
    int* gNc  = gTc + NCHMAX * NG;                      // NCHMAX*NG
    float2* iLM = (float2*)(gNc + NCHMAX * NG);         // B float2 (8B aligned)
    float2* jLM = iLM + B;                              // B float2
    float*  part = (float*)(jLM + B);                   // 27*NBLK floats

    k_classify<<<dim3(nCh), dim3(256), 0, stream>>>(
        logits, ytox, yid, B, hdr, gTc, gNc, iLM, jLM);
    k_pairs<<<dim3(NBLK), dim3(256), 0, stream>>>(hdr, iLM, jLM, part);
    k_final<<<dim3(1), dim3(512), 0, stream>>>(part, hdr, gTc, gNc, B,
                                               (float*)d_out);
}

// Round 12
// 86.884 us; speedup vs baseline: 1.1608x; 1.0469x over previous
//
#include <hip/hip_runtime.h>
#include <math.h>

#define NG 9
#define NBLK 1024          // pair blocks: 4/CU
#define JT 32              // j-tile width (nbI*nbJ = 8*128 = 1024 at B=8192)
#define ITILE 512          // i-fragment: 2 slots x 256 threads (packed as float2)
#define LOG2E 1.4426950408889634f
#define LN2   0.6931471805599453f

typedef float f32x2 __attribute__((ext_vector_type(2)));

// ---------------------------------------------------------------------------
// Dispatch 2: classify once, atomic-reserve dense segments (R1 structure).
// cnts: [0]=nI, [1]=nJ, [2..10]=cT[g], [11..19]=cN[g]   (zeroed by 80B memset)
// ---------------------------------------------------------------------------
__global__ __launch_bounds__(256) void k_classify(
    const float* __restrict__ logits, const float* __restrict__ ytox,
    const float* __restrict__ yid, int B, int* __restrict__ cnts,
    float2* __restrict__ iLM, float2* __restrict__ jLM) {

    __shared__ int wT[4], wN[4], offT[4], offN[4], bT, bN;
    __shared__ int gT[4][NG], gN[4][NG];

    const int tid = threadIdx.x, lane = tid & 63, wave = tid >> 6;
    const int row = blockIdx.x * 256 + tid;
    const bool v = row < B;

    float l = 0.f; bool tox = false, non = false; int m = 0;
    if (v) {
        l = logits[row] * LOG2E;          // pre-scale: softplus in log2 domain
        tox = ytox[row] >= 0.5f;
        non = !tox;
#pragma unroll
        for (int g = 0; g < NG; ++g)
            if (yid[row * NG + g] >= 0.5f) m |= 1 << g;
    }
    const unsigned long long bTox = __ballot(tox), bNon = __ballot(non);
    const unsigned long long lt = (1ull << lane) - 1ull;
    const int pT = __popcll(bTox & lt), pN = __popcll(bNon & lt);
    if (lane == 0) { wT[wave] = __popcll(bTox); wN[wave] = __popcll(bNon); }
#pragma unroll
    for (int g = 0; g < NG; ++g) {
        const unsigned long long bt = __ballot(tox && ((m >> g) & 1));
        const unsigned long long bn = __ballot(non && ((m >> g) & 1));
        if (lane == 0) { gT[wave][g] = __popcll(bt); gN[wave][g] = __popcll(bn); }
    }
    __syncthreads();
    if (tid == 0) {
        int a = 0, b = 0;
#pragma unroll
        for (int w = 0; w < 4; ++w) { offT[w] = a; a += wT[w]; offN[w] = b; b += wN[w]; }
        bT = atomicAdd(&cnts[0], a);
        bN = atomicAdd(&cnts[1], b);
    }
    __syncthreads();
    if (tox) iLM[bT + offT[wave] + pT] = make_float2(l, __int_as_float(m));
    if (non) jLM[bN + offN[wave] + pN] = make_float2(l, __int_as_float(m));
    if (tid < NG)
        atomicAdd(&cnts[2 + tid], gT[0][tid] + gT[1][tid] + gT[2][tid] + gT[3][tid]);
    else if (tid >= 64 && tid < 64 + NG) {
        const int g = tid - 64;
        atomicAdd(&cnts[11 + g], gN[0][g] + gN[1][g] + gN[2][g] + gN[3][g]);
    }
}

// ---------------------------------------------------------------------------
// Dispatch 3: pair kernel over globally-dense lists — no prefix, no search.
// Two i-slots per thread packed into f32x2 lanes; inner loop uses packed
// FP32 (v_pk_sub/add/fma) -> ~12 VALU + 4 trans issues per j per thread.
// ---------------------------------------------------------------------------
__global__ __launch_bounds__(256, 4) void k_pairs(
    const int* __restrict__ cnts, const float2* __restrict__ iLM,
    const float2* __restrict__ jLM, float* __restrict__ part) {

    __shared__ float2 jS[JT];
    __shared__ float red[4][27];
    __shared__ float acc[27];

    const int tid = threadIdx.x, lane = tid & 63, wave = tid >> 6;
    const int blk = blockIdx.x;
    const int nI = cnts[0], nJ = cnts[1];
    const int nbI = (nI + ITILE - 1) / ITILE;
    const int nbJ = (nJ + JT - 1) / JT;
    const int nT = nbI * nbJ;

    if (tid < 27) acc[tid] = 0.f;

    f32x2 li = {1e30f, 1e30f};        // sentinel: exp2(-inf)=0 -> contributes 0
    int mi0 = 0, mi1 = 0;
    f32x2 Ra = {0.f, 0.f};
    f32x2 Rg[NG];
#pragma unroll
    for (int g = 0; g < NG; ++g) Rg[g] = (f32x2){0.f, 0.f};

    auto flush = [&]() {   // fold 2 packed slots x 9 groups into 27 block sums
#pragma unroll
        for (int g = 0; g < NG; ++g) {
            const bool i0 = (mi0 >> g) & 1, i1 = (mi1 >> g) & 1;
            const float r0 = Rg[g].x, r1 = Rg[g].y;
            float x0 = (i0 ? r0 : 0.f) + (i1 ? r1 : 0.f);
            float x1 = (i0 ? 0.f : r0) + (i1 ? 0.f : r1);
            float x2 = (i0 ? (Ra.x - r0) : 0.f) + (i1 ? (Ra.y - r1) : 0.f);
#pragma unroll
            for (int off = 32; off > 0; off >>= 1) {
                x0 += __shfl_xor(x0, off, 64);
                x1 += __shfl_xor(x1, off, 64);
                x2 += __shfl_xor(x2, off, 64);
            }
            if (lane == 0) {
                red[wave][g] = x0; red[wave][NG + g] = x1; red[wave][2 * NG + g] = x2;
            }
        }
        __syncthreads();
        if (tid < 27)
            acc[tid] += red[0][tid] + red[1][tid] + red[2][tid] + red[3][tid];
    };

    int prev_bi = -1;
    for (int t = blk; t < nT; t += NBLK) {
        const int bi = t % nbI, bj = t / nbI;   // j-major: bi stable per block
        if (bi != prev_bi) {
            if (prev_bi >= 0) flush();
            const int k0 = bi * ITILE + tid, k1 = k0 + 256;
            const float2 a0 = (k0 < nI) ? iLM[k0] : make_float2(1e30f, 0.f);
            const float2 a1 = (k1 < nI) ? iLM[k1] : make_float2(1e30f, 0.f);
            li.x = a0.x; mi0 = __float_as_int(a0.y);
            li.y = a1.x; mi1 = __float_as_int(a1.y);
            Ra = (f32x2){0.f, 0.f};
#pragma unroll
            for (int g = 0; g < NG; ++g) Rg[g] = (f32x2){0.f, 0.f};
            prev_bi = bi;
        }
        const int jbeg = bj * JT;
        const int jcnt = min(JT, nJ - jbeg);
        __syncthreads();                         // jS reuse + red/acc ordering
        if (tid < jcnt) jS[tid] = jLM[jbeg + tid];
        __syncthreads();
#pragma unroll 2
        for (int k = 0; k < jcnt; ++k) {
            const float2 jv = jS[k];                                  // b64 broadcast
            const int mj = __builtin_amdgcn_readfirstlane(__float_as_int(jv.y));
            const f32x2 ljv = {jv.x, jv.x};
            const f32x2 d = ljv - li;                                 // v_pk_sub? (2->1)
            f32x2 e;
            e.x = __builtin_amdgcn_exp2f(d.x);                        // trans x2
            e.y = __builtin_amdgcn_exp2f(d.y);
            const f32x2 one = {1.f, 1.f};
            const f32x2 tpe = e + one;                                // v_pk_add
            f32x2 s;
            s.x = __builtin_amdgcn_logf(tpe.x);                       // trans x2
            s.y = __builtin_amdgcn_logf(tpe.y);
            Ra = Ra + s;                                              // v_pk_add
#pragma unroll
            for (int g = 0; g < NG; ++g) {
                const float bg = ((mj >> g) & 1) ? 1.f : 0.f;          // SGPR select
                const f32x2 bgv = {bg, bg};
                Rg[g] = __builtin_elementwise_fma(bgv, s, Rg[g]);      // v_pk_fma
            }
        }
    }
    if (prev_bi >= 0) flush();
    if (tid < 27) part[tid * NBLK + blk] = acc[tid];   // zeros when no tiles
}

// ---------------------------------------------------------------------------
// Dispatch 4: reduce 27 x NBLK partials (x ln2) + integer counts + fp64 tail.
// ---------------------------------------------------------------------------
__global__ __launch_bounds__(512) void k_final(
    const float* __restrict__ part, const int* __restrict__ cnts,
    float* __restrict__ out) {
    __shared__ float fin[27];
    const int tid = threadIdx.x, lane = tid & 63, wave = tid >> 6;
    for (int r = wave; r < 27; r += 8) {
        float s = 0.f;
#pragma unroll
        for (int q = 0; q < NBLK / 64; ++q) s += part[r * NBLK + (q << 6) + lane];
#pragma unroll
        for (int off = 32; off > 0; off >>= 1) s += __shfl_xor(s, off, 64);
        if (lane == 0) fin[r] = s * LN2;     // undo log2-domain accumulation
    }
    __syncthreads();
    if (tid == 0) {
        const long long nT64 = cnts[0], nN64 = cnts[1];
        double accd = 0.0; int ngv = 0;
        for (int g = 0; g < NG; ++g) {
            const long long cT = cnts[2 + g], cN = cnts[11 + g];
            const long long c0 = cT * cN;
            const long long c1 = (nT64 - cT) * cN;
            const long long c2 = cT * (nN64 - cN);
            const double t0 = (double)fin[g]          / (double)(c0 > 0 ? c0 : 1);
            const double t1 = (double)fin[NG + g]     / (double)(c1 > 0 ? c1 : 1);
            const double t2 = (double)fin[2 * NG + g] / (double)(c2 > 0 ? c2 : 1);
            const int nv = (c0 > 0) + (c1 > 0) + (c2 > 0);
            const double gl = ((c0 > 0 ? t0 : 0.0) + (c1 > 0 ? t1 : 0.0) +
                               (c2 > 0 ? t2 : 0.0)) / (double)(nv > 0 ? nv : 1);
            if (nv > 0) { const double g2 = gl * gl; accd += g2 * g2; ++ngv; }
        }
        const double mp = accd / (double)(ngv > 0 ? ngv : 1);
        const double loss = sqrt(sqrt(mp));  // ^(1/4)
        out[0] = (float)(ngv > 0 ? loss : 0.0);
    }
}

extern "C" void kernel_launch(void* const* d_in, const int* in_sizes, int n_in,
                              void* d_out, int out_size, void* d_ws, size_t ws_size,
                              hipStream_t stream) {
    const float* logits = (const float*)d_in[0];
    const float* ytox   = (const float*)d_in[1];
    const float* yid    = (const float*)d_in[2];
    const int B = in_sizes[0];

    char* ws = (char*)d_ws;
    int*    cnts = (int*)ws;                      // 20 ints (pad to 128B)
    float2* iLM  = (float2*)(ws + 128);           // B float2
    float2* jLM  = iLM + B;                       // B float2
    float*  part = (float*)(jLM + B);             // 27*NBLK floats

    hipMemsetAsync(cnts, 0, 20 * sizeof(int), stream);
    k_classify<<<dim3((B + 255) / 256), dim3(256), 0, stream>>>(
        logits, ytox, yid, B, cnts, iLM, jLM);
    k_pairs<<<dim3(NBLK), dim3(256), 0, stream>>>(cnts, iLM, jLM, part);
    k_final<<<dim3(1), dim3(512), 0, stream>>>(part, cnts, (float*)d_out);
}